// Round 7
// baseline (563.607 us; speedup 1.0000x reference)
//
#include <hip/hip_runtime.h>

#define NN 50000
#define NE 800000
#define BINS 98      // bins of 512 nodes per branch
#define CAP 12288    // per-bin capacity (u32 records / ushort csr entries)
#define EPB 4096     // edges per phase-1 block
#define P1B ((NE + EPB - 1) / EPB)  // 196 blocks per branch

typedef __attribute__((ext_vector_type(8))) short short8;
typedef __attribute__((ext_vector_type(4))) float f32x4;
typedef __attribute__((ext_vector_type(8))) unsigned short ushort8v;
typedef __attribute__((ext_vector_type(4))) unsigned short ushort4v;
typedef _Float16 half8 __attribute__((ext_vector_type(8)));

__device__ __forceinline__ ushort f2bf(float f) {
    unsigned u = __float_as_uint(f);
    unsigned r = (u + 0x7fffu + ((u >> 16) & 1u)) >> 16;
    return (ushort)r;
}
__device__ __forceinline__ float bf2f(ushort h) {
    return __uint_as_float(((unsigned)h) << 16);
}
__device__ __forceinline__ ushort f2h(float f) {
    _Float16 h = (_Float16)f;
    return __builtin_bit_cast(ushort, h);
}
__device__ __forceinline__ float h2f(ushort u) {
    return (float)__builtin_bit_cast(_Float16, u);
}

// ---------------- phase 1: bin edges by dst>>9, coalesced line-exclusive flush ----

__global__ __launch_bounds__(256) void k_bin(const int* __restrict__ e0,
                                             const int* __restrict__ e1,
                                             const int* __restrict__ e2,
                                             int* __restrict__ g_cur,
                                             unsigned* __restrict__ g_bins) {
    const int br = blockIdx.x / P1B;
    const int cb = blockIdx.x % P1B;
    const int* ep = (br == 0 ? e0 : br == 1 ? e1 : e2);
    const int tid = threadIdx.x;
    const int e_base = cb * EPB;

    __shared__ int s_cnt[BINS];
    __shared__ int s_start[BINS];
    __shared__ int s_cur[BINS];
    __shared__ int s_gb[BINS];
    __shared__ unsigned s_stage[EPB];

    if (tid < BINS) s_cnt[tid] = 0;
    __syncthreads();

    int4 s4[4], d4[4];
    bool valid[4];
#pragma unroll
    for (int i = 0; i < 4; ++i) {
        int idx = e_base + i * 1024 + tid * 4;
        valid[i] = (idx < NE);  // idx%4==0, NE%4==0 -> full int4 valid
        if (valid[i]) {
            s4[i] = *(const int4*)&ep[idx];
            d4[i] = *(const int4*)&ep[NE + idx];
            atomicAdd(&s_cnt[d4[i].x >> 9], 1);
            atomicAdd(&s_cnt[d4[i].y >> 9], 1);
            atomicAdd(&s_cnt[d4[i].z >> 9], 1);
            atomicAdd(&s_cnt[d4[i].w >> 9], 1);
        }
    }
    __syncthreads();
    if (tid == 0) {
        int run = 0;
        for (int b = 0; b < BINS; ++b) {
            s_start[b] = run;
            run += s_cnt[b];
        }
    }
    __syncthreads();
    if (tid < BINS) {
        s_cur[tid] = s_start[tid];
        int c = s_cnt[tid];
        int pc = (c + 15) & ~15;  // 64B-aligned reservation
        s_gb[tid] = (c > 0) ? atomicAdd(&g_cur[br * BINS + tid], pc) : 0;
    }
    __syncthreads();

#pragma unroll
    for (int i = 0; i < 4; ++i) {
        if (valid[i]) {
            int ss[4] = {s4[i].x, s4[i].y, s4[i].z, s4[i].w};
            int dd[4] = {d4[i].x, d4[i].y, d4[i].z, d4[i].w};
#pragma unroll
            for (int q = 0; q < 4; ++q) {
                int bin = dd[q] >> 9;
                int pos = atomicAdd(&s_cur[bin], 1);
                s_stage[pos] = ((unsigned)(dd[q] & 511) << 16) | (unsigned)ss[q];
            }
        }
    }
    __syncthreads();

    for (int b = 0; b < BINS; ++b) {
        int c = s_cnt[b];
        if (c == 0) continue;
        int st = s_start[b];
        int gb = s_gb[b];
        int pc = (c + 15) & ~15;
        if (gb + pc > CAP) pc = (gb < CAP) ? (CAP - gb) : 0;  // overflow guard
        size_t obase = (size_t)(br * BINS + b) * CAP + gb;
        for (int j = tid; j < pc; j += 256)
            g_bins[obase + j] = (j < c) ? s_stage[st + j] : 0x80000000u;
    }
}

// ---------------- phase 2: per-bin CSR build + per-node src-sort ----------------

__device__ __forceinline__ int wave_incl_scan(int v, int lane) {
#pragma unroll
    for (int d = 1; d < 64; d <<= 1) {
        int u = __shfl_up(v, d);
        if (lane >= d) v += u;
    }
    return v;
}

__global__ __launch_bounds__(256) void k_build(const unsigned* __restrict__ g_bins,
                                               const int* __restrict__ g_cur,
                                               ushort* __restrict__ g_csr,
                                               int* __restrict__ seg3,
                                               int* __restrict__ cnt3,
                                               float* __restrict__ dinv3) {
    const int bid = blockIdx.x;  // branch*BINS + bin
    const int br = bid / BINS;
    const int b2 = bid % BINS;
    const size_t base = (size_t)bid * CAP;
    const int node0 = b2 << 9;
    const int tid = threadIdx.x;

    __shared__ int s_cnt[512];
    __shared__ int s_off[512];
    __shared__ int s_wsum[4];
    __shared__ int s_valid;
    __shared__ ushort s_srt[CAP];

    s_cnt[tid] = 0;
    s_cnt[tid + 256] = 0;
    __syncthreads();

    const int total = min(g_cur[bid], CAP);
    for (int j = tid; j < total; j += 256) {
        unsigned p = g_bins[base + j];
        if (!(p & 0x80000000u)) atomicAdd(&s_cnt[(p >> 16) & 0x1FF], 1);
    }
    __syncthreads();

    // exclusive scan of 512 counts (pairs per thread + wave scan)
    const int lane = tid & 63, w = tid >> 6;
    int c0 = s_cnt[2 * tid], c1 = s_cnt[2 * tid + 1];
    int c2 = c0 + c1;
    int incl = wave_incl_scan(c2, lane);
    if (lane == 63) s_wsum[w] = incl;
    __syncthreads();
    int wpre = 0;
    for (int i = 0; i < w; ++i) wpre += s_wsum[i];
    int ex = wpre + incl - c2;
    s_off[2 * tid] = ex;
    s_off[2 * tid + 1] = ex + c0;
    if (tid == 0) s_valid = s_wsum[0] + s_wsum[1] + s_wsum[2] + s_wsum[3];

#pragma unroll
    for (int q = 0; q < 2; ++q) {
        int local = 2 * tid + q;
        int node = node0 + local;
        if (node < NN) {
            int g = br * NN + node;
            int c = (q == 0) ? c0 : c1;
            seg3[g] = (int)base + s_off[local];
            cnt3[g] = c;
            dinv3[g] = rsqrtf((float)(c + 1));
        }
    }
    __syncthreads();
    // cursors
    s_cnt[2 * tid] = s_off[2 * tid];
    s_cnt[2 * tid + 1] = s_off[2 * tid + 1];
    __syncthreads();

    // place into LDS
    for (int j = tid; j < total; j += 256) {
        unsigned p = g_bins[base + j];
        if (!(p & 0x80000000u)) {
            int loc = (p >> 16) & 0x1FF;
            int pos = atomicAdd(&s_cnt[loc], 1);
            s_srt[pos] = (ushort)(p & 0xFFFFu);
        }
    }
    __syncthreads();

    // per-node insertion sort by src (ascending) -> coordinated sweep in aggs
#pragma unroll
    for (int q = 0; q < 2; ++q) {
        int local = 2 * tid + q;
        int st = s_off[local];
        int c = (q == 0) ? c0 : c1;
        for (int a = st + 1; a < st + c; ++a) {
            ushort key = s_srt[a];
            int b = a - 1;
            while (b >= st && s_srt[b] > key) {
                s_srt[b + 1] = s_srt[b];
                --b;
            }
            s_srt[b + 1] = key;
        }
    }
    __syncthreads();

    const int valid = s_valid;
    for (int j = tid; j < valid; j += 256) g_csr[base + j] = s_srt[j];
}

// ---------------- conversions ----------------

__global__ __launch_bounds__(256) void k_conv_x(const float* __restrict__ x,
                                                ushort* __restrict__ xp) {
    const int wid = threadIdx.x >> 6, lane = threadIdx.x & 63;
    const int row = blockIdx.x * 4 + wid;
    if (row >= NN) return;
    float4 v = *(const float4*)&x[(size_t)row * 256 + lane * 4];
    ushort4 hi, lo;
    hi.x = f2bf(v.x); lo.x = f2bf(v.x - bf2f(hi.x));
    hi.y = f2bf(v.y); lo.y = f2bf(v.y - bf2f(hi.y));
    hi.z = f2bf(v.z); lo.z = f2bf(v.z - bf2f(hi.z));
    hi.w = f2bf(v.w); lo.w = f2bf(v.w - bf2f(hi.w));
    *(ushort4*)&xp[(size_t)row * 512 + lane * 4] = hi;
    *(ushort4*)&xp[(size_t)row * 512 + 256 + lane * 4] = lo;
}

__global__ __launch_bounds__(256) void k_conv_w1(const float* __restrict__ w0,
                                                 const float* __restrict__ w1,
                                                 const float* __restrict__ w2,
                                                 ushort* __restrict__ BT1all) {
    int idx = blockIdx.x * 256 + threadIdx.x;  // 3 * 65536
    int b = idx >> 16, r = idx & 65535;
    int k = r >> 8, n = r & 255;
    const float* W = (b == 0 ? w0 : b == 1 ? w1 : w2);
    float w = W[r];
    ushort hi = f2bf(w);
    ushort lo = f2bf(w - bf2f(hi));
    ushort* row = BT1all + (size_t)b * 196608 + (size_t)n * 768;
    row[k] = hi;
    row[256 + k] = hi;
    row[512 + k] = lo;
}

__global__ __launch_bounds__(256) void k_conv_w2(const float* __restrict__ w0,
                                                 const float* __restrict__ w1,
                                                 const float* __restrict__ w2,
                                                 ushort* __restrict__ BT2all) {
    int idx = blockIdx.x * 256 + threadIdx.x;  // 3 * 32768
    int b = idx >> 15, r = idx & 32767;
    int k = r >> 7, n = r & 127;
    const float* W = (b == 0 ? w0 : b == 1 ? w1 : w2);
    BT2all[(size_t)b * 32768 + (size_t)n * 256 + k] = f2h(W[r]);
}

// ---------------- MFMA GEMM (bf16x3 or fp16), batched over 3 branches ----------------

template <int BM, int BN, int N, int KK, int AK, bool HALF>
__global__ __launch_bounds__((BM / 64) * (BN / 64) * 64) void k_gemm(
    const ushort* __restrict__ A, size_t aBatch,
    const ushort* __restrict__ BTall, int btBatch,
    const float* __restrict__ dinv3, ushort* __restrict__ Call, size_t cBatch) {
    constexpr int WGN = BN / 64, NW = (BM / 64) * WGN;
    constexpr int BK = 32;
    constexpr int MT = (NN + BM - 1) / BM, NT = N / BN, GB = MT * NT;
    __shared__ ushort sA[BM * BK];
    __shared__ ushort sB[BN * BK];
    const int kb = blockIdx.x / GB;
    const int bid = blockIdx.x % GB;
    const ushort* Ab = A + (size_t)kb * aBatch;
    const ushort* BT = BTall + (size_t)kb * btBatch;
    const float* dinv = dinv3 + (size_t)kb * NN;
    ushort* C = Call + (size_t)kb * cBatch;
    const int t = threadIdx.x, lane = t & 63, wid = t >> 6;
    const int wm = (wid / WGN) * 64, wn = (wid % WGN) * 64;
    const int bm = (bid / NT) * BM;
    const int bn = (bid % NT) * BN;

    f32x4 zero = {0.f, 0.f, 0.f, 0.f};
    f32x4 acc[4][4];
#pragma unroll
    for (int m = 0; m < 4; ++m)
#pragma unroll
        for (int n = 0; n < 4; ++n) acc[m][n] = zero;

    constexpr int A_ISS = (BM * BK * 2) / (NW * 1024);
    constexpr int B_ISS = (BN * BK * 2) / (NW * 1024);

    for (int kt = 0; kt < KK; kt += BK) {
        const int akt = (kt >= AK) ? kt - AK : kt;
        __syncthreads();
#pragma unroll
        for (int i = 0; i < A_ISS; ++i) {
            int off = (wid + i * NW) << 10;
            int la = off + lane * 16;
            int row = la >> 6;
            int slot = (la >> 4) & 3;
            int scol = (slot ^ (row & 3)) << 4;
            int grow = bm + row;
            if (grow > NN - 1) grow = NN - 1;
            const char* ga = (const char*)Ab + (size_t)grow * (AK * 2) + akt * 2 + scol;
            __builtin_amdgcn_global_load_lds(
                (__attribute__((address_space(1))) const void*)ga,
                (__attribute__((address_space(3))) void*)((char*)sA + off), 16, 0, 0);
        }
#pragma unroll
        for (int i = 0; i < B_ISS; ++i) {
            int off = (wid + i * NW) << 10;
            int la = off + lane * 16;
            int row = la >> 6;
            int slot = (la >> 4) & 3;
            int scol = (slot ^ (row & 3)) << 4;
            const char* ga = (const char*)BT + (size_t)(bn + row) * (KK * 2) + kt * 2 + scol;
            __builtin_amdgcn_global_load_lds(
                (__attribute__((address_space(1))) const void*)ga,
                (__attribute__((address_space(3))) void*)((char*)sB + off), 16, 0, 0);
        }
        __syncthreads();

        const int s = lane >> 4;
        const int r0 = lane & 15;
        short8 af[4], bf[4];
#pragma unroll
        for (int m = 0; m < 4; ++m) {
            int row = wm + m * 16 + r0;
            af[m] = *(const short8*)((const char*)sA + row * 64 + ((s ^ (row & 3)) << 4));
        }
#pragma unroll
        for (int n = 0; n < 4; ++n) {
            int row = wn + n * 16 + r0;
            bf[n] = *(const short8*)((const char*)sB + row * 64 + ((s ^ (row & 3)) << 4));
        }
#pragma unroll
        for (int m = 0; m < 4; ++m)
#pragma unroll
            for (int n = 0; n < 4; ++n) {
                if constexpr (HALF)
                    acc[m][n] = __builtin_amdgcn_mfma_f32_16x16x32_f16(
                        __builtin_bit_cast(half8, af[m]), __builtin_bit_cast(half8, bf[n]),
                        acc[m][n], 0, 0, 0);
                else
                    acc[m][n] = __builtin_amdgcn_mfma_f32_16x16x32_bf16(af[m], bf[n],
                                                                        acc[m][n], 0, 0, 0);
            }
    }

    const int cr0 = (lane >> 4) * 4;
    const int cc = lane & 15;
#pragma unroll
    for (int m = 0; m < 4; ++m) {
#pragma unroll
        for (int r = 0; r < 4; ++r) {
            int row = bm + wm + m * 16 + cr0 + r;
            if (row < NN) {
                float dv = dinv[row];
#pragma unroll
                for (int n = 0; n < 4; ++n)
                    C[(size_t)row * N + bn + wn + n * 16 + cc] = f2h(acc[m][n][r] * dv);
            }
        }
    }
}

// ---------------- layer-1 aggregation (batched over 3 branches) ----------------

__global__ __launch_bounds__(256) void k_agg1(const ushort* __restrict__ hs16all,
                                              const int* __restrict__ seg3,
                                              const int* __restrict__ cnt3,
                                              const ushort* __restrict__ g_csr,
                                              const float* __restrict__ dinv3,
                                              const float* __restrict__ b1a,
                                              const float* __restrict__ b1b,
                                              const float* __restrict__ b1c,
                                              ushort* __restrict__ h1all) {
    constexpr int WBn = (NN + 3) / 4;
    const int b = blockIdx.x / WBn;
    const int blk = blockIdx.x % WBn;
    const int wid = threadIdx.x >> 6;
    const int lane = threadIdx.x & 63;
    const int node = blk * 4 + wid;
    if (node >= NN) return;
    const int half = lane >> 5, l32 = lane & 31;
    const int g = b * NN + node;
    const ushort* hs = hs16all + (size_t)b * NN * 256;
    const ushort* csr = g_csr + seg3[g];
    const int len = cnt3[g] + 1;
    const size_t colb = (size_t)l32 * 8;

    float acc[8] = {0.f, 0.f, 0.f, 0.f, 0.f, 0.f, 0.f, 0.f};
    int i = half;
    for (; i + 6 < len; i += 8) {
        int s0 = (i == 0) ? node : (int)csr[i - 1];
        int s1 = (int)csr[i + 1];
        int s2 = (int)csr[i + 3];
        int s3 = (int)csr[i + 5];
        ushort8v v0 = *(const ushort8v*)&hs[(size_t)s0 * 256 + colb];
        ushort8v v1 = *(const ushort8v*)&hs[(size_t)s1 * 256 + colb];
        ushort8v v2 = *(const ushort8v*)&hs[(size_t)s2 * 256 + colb];
        ushort8v v3 = *(const ushort8v*)&hs[(size_t)s3 * 256 + colb];
#pragma unroll
        for (int j = 0; j < 8; ++j)
            acc[j] += (h2f(v0[j]) + h2f(v1[j])) + (h2f(v2[j]) + h2f(v3[j]));
    }
    for (; i < len; i += 2) {
        int s = (i == 0) ? node : (int)csr[i - 1];
        ushort8v v = *(const ushort8v*)&hs[(size_t)s * 256 + colb];
#pragma unroll
        for (int j = 0; j < 8; ++j) acc[j] += h2f(v[j]);
    }
#pragma unroll
    for (int j = 0; j < 8; ++j) acc[j] += __shfl_xor(acc[j], 32);

    if (half == 0) {
        const float* bias = (b == 0 ? b1a : b == 1 ? b1b : b1c);
        const float di = dinv3[g];
        ushort8v o;
#pragma unroll
        for (int j = 0; j < 8; ++j) {
            float r = fmaxf(di * acc[j] + bias[l32 * 8 + j], 0.f);
            o[j] = f2h(r);
        }
        *(ushort8v*)&h1all[((size_t)b * NN + node) * 256 + colb] = o;
    }
}

// ---------------- fused layer-2 aggregation (x3) + attention ----------------

__global__ __launch_bounds__(256) void k_final(const ushort* __restrict__ hs2all,
                                               const int* __restrict__ seg3,
                                               const int* __restrict__ cnt3,
                                               const ushort* __restrict__ g_csr,
                                               const float* __restrict__ dinv3,
                                               const float* __restrict__ b2a,
                                               const float* __restrict__ b2b,
                                               const float* __restrict__ b2c,
                                               const float* __restrict__ attn_w,
                                               const float* __restrict__ attn_b,
                                               float* __restrict__ out) {
    const int wid = threadIdx.x >> 6;
    const int lane = threadIdx.x & 63;
    const int node = blockIdx.x * 4 + wid;
    if (node >= NN) return;
    const int half = lane >> 5, l32 = lane & 31;
    const size_t colb = (size_t)l32 * 4;

    float f[3][4];
#pragma unroll
    for (int b = 0; b < 3; ++b) {
        const int g = b * NN + node;
        const ushort* hs = hs2all + (size_t)b * NN * 128;
        const ushort* csr = g_csr + seg3[g];
        const int len = cnt3[g] + 1;
        float acc[4] = {0.f, 0.f, 0.f, 0.f};
        int i = half;
        for (; i + 6 < len; i += 8) {
            int s0 = (i == 0) ? node : (int)csr[i - 1];
            int s1 = (int)csr[i + 1];
            int s2 = (int)csr[i + 3];
            int s3 = (int)csr[i + 5];
            ushort4v v0 = *(const ushort4v*)&hs[(size_t)s0 * 128 + colb];
            ushort4v v1 = *(const ushort4v*)&hs[(size_t)s1 * 128 + colb];
            ushort4v v2 = *(const ushort4v*)&hs[(size_t)s2 * 128 + colb];
            ushort4v v3 = *(const ushort4v*)&hs[(size_t)s3 * 128 + colb];
#pragma unroll
            for (int j = 0; j < 4; ++j)
                acc[j] += (h2f(v0[j]) + h2f(v1[j])) + (h2f(v2[j]) + h2f(v3[j]));
        }
        for (; i < len; i += 2) {
            int s = (i == 0) ? node : (int)csr[i - 1];
            ushort4v v = *(const ushort4v*)&hs[(size_t)s * 128 + colb];
#pragma unroll
            for (int j = 0; j < 4; ++j) acc[j] += h2f(v[j]);
        }
#pragma unroll
        for (int j = 0; j < 4; ++j) acc[j] += __shfl_xor(acc[j], 32);
        const float* bias = (b == 0 ? b2a : b == 1 ? b2b : b2c);
        const float di = dinv3[g];
#pragma unroll
        for (int j = 0; j < 4; ++j) f[b][j] = di * acc[j] + bias[l32 * 4 + j];
    }

    float4 w = *(const float4*)&attn_w[l32 * 4];
    float s0 = f[0][0] * w.x + f[0][1] * w.y + f[0][2] * w.z + f[0][3] * w.w;
    float s1 = f[1][0] * w.x + f[1][1] * w.y + f[1][2] * w.z + f[1][3] * w.w;
    float s2 = f[2][0] * w.x + f[2][1] * w.y + f[2][2] * w.z + f[2][3] * w.w;
#pragma unroll
    for (int m = 16; m >= 1; m >>= 1) {
        s0 += __shfl_xor(s0, m);
        s1 += __shfl_xor(s1, m);
        s2 += __shfl_xor(s2, m);
    }
    float bb = attn_b[0];
    s0 += bb; s1 += bb; s2 += bb;
    float mx = fmaxf(s0, fmaxf(s1, s2));
    float e0 = expf(s0 - mx), e1 = expf(s1 - mx), e2 = expf(s2 - mx);
    float inv = 1.f / (e0 + e1 + e2);
    e0 *= inv; e1 *= inv; e2 *= inv;

    if (half == 0) {
        float4 o;
        o.x = f[0][0] * e0 + f[1][0] * e1 + f[2][0] * e2;
        o.y = f[0][1] * e0 + f[1][1] * e1 + f[2][1] * e2;
        o.z = f[0][2] * e0 + f[1][2] * e1 + f[2][2] * e2;
        o.w = f[0][3] * e0 + f[1][3] * e1 + f[2][3] * e2;
        *(float4*)&out[(size_t)node * 128 + colb] = o;
    }
}

// ---------------- launch ----------------

extern "C" void kernel_launch(void* const* d_in, const int* in_sizes, int n_in,
                              void* d_out, int out_size, void* d_ws, size_t ws_size,
                              hipStream_t stream) {
    const float* x = (const float*)d_in[0];
    const int* e0 = (const int*)d_in[1];
    const int* e1 = (const int*)d_in[2];
    const int* e2 = (const int*)d_in[3];
    const float* attn_w = (const float*)d_in[16];
    const float* attn_b = (const float*)d_in[17];

    char* ws = (char*)d_ws;
    size_t off = 0;
    auto alloc = [&](size_t bytes) -> void* {
        void* p = ws + off;
        off += (bytes + 255) & ~(size_t)255;
        return p;
    };

    int* g_cur      = (int*)alloc(3 * BINS * 4);                 // zeroed
    int* seg3       = (int*)alloc((size_t)3 * NN * 4);
    int* cnt3       = (int*)alloc((size_t)3 * NN * 4);
    float* dinv3    = (float*)alloc((size_t)3 * NN * 4);
    ushort* g_csr   = (ushort*)alloc((size_t)3 * BINS * CAP * 2);  // 7.2 MB
    ushort* xp      = (ushort*)alloc((size_t)NN * 512 * 2);       // 51.2 MB
    ushort* hs2all  = xp;  // alias: xp dead after gemm1; hs2 (38.4 MB) fits
    ushort* hs16all = (ushort*)alloc((size_t)3 * NN * 256 * 2);   // 76.8 MB
    ushort* h1all   = (ushort*)alloc((size_t)3 * NN * 256 * 2);   // 76.8 MB
    unsigned* g_bins = (unsigned*)h1all;  // alias: g_bins dead before h1all written
    ushort* BT1all  = (ushort*)alloc((size_t)3 * 256 * 768 * 2);
    ushort* BT2all  = (ushort*)alloc((size_t)3 * 128 * 256 * 2);

    const int WB = (NN + 3) / 4;  // 12500

    hipMemsetAsync(g_cur, 0, 3 * BINS * 4, stream);
    k_conv_x<<<WB, 256, 0, stream>>>(x, xp);
    k_conv_w1<<<768, 256, 0, stream>>>((const float*)d_in[4], (const float*)d_in[8],
                                       (const float*)d_in[12], BT1all);
    k_conv_w2<<<384, 256, 0, stream>>>((const float*)d_in[6], (const float*)d_in[10],
                                       (const float*)d_in[14], BT2all);

    k_bin<<<3 * P1B, 256, 0, stream>>>(e0, e1, e2, g_cur, g_bins);
    k_build<<<3 * BINS, 256, 0, stream>>>(g_bins, g_cur, g_csr, seg3, cnt3, dinv3);

    // layer 1: hs = dinv*(x @ W1) bf16x3 -> fp16, all branches
    k_gemm<128, 128, 256, 768, 512, false><<<3 * 391 * 2, 256, 0, stream>>>(
        xp, 0, BT1all, 196608, dinv3, hs16all, (size_t)NN * 256);
    k_agg1<<<3 * WB, 256, 0, stream>>>(hs16all, seg3, cnt3, g_csr, dinv3,
                                       (const float*)d_in[5], (const float*)d_in[9],
                                       (const float*)d_in[13], h1all);

    // layer 2: hs2 = dinv*(h1 @ W2) fp16, all branches
    k_gemm<128, 128, 128, 256, 256, true><<<3 * 391, 256, 0, stream>>>(
        h1all, (size_t)NN * 256, BT2all, 32768, dinv3, hs2all, (size_t)NN * 128);

    // fused layer-2 aggregation + attention
    k_final<<<WB, 256, 0, stream>>>(hs2all, seg3, cnt3, g_csr, dinv3,
                                    (const float*)d_in[7], (const float*)d_in[11],
                                    (const float*)d_in[15], attn_w, attn_b,
                                    (float*)d_out);
}

// Round 8
// 483.217 us; speedup vs baseline: 1.1664x; 1.1664x over previous
//
#include <hip/hip_runtime.h>

#define NN 50000
#define NE 800000
#define BINS 98      // bins of 512 nodes per branch
#define CAP 12288    // per-bin capacity (u32 records / ushort csr entries)
#define EPB 4096     // edges per phase-1 block
#define P1B ((NE + EPB - 1) / EPB)  // 196 blocks per branch

typedef __attribute__((ext_vector_type(8))) short short8;
typedef __attribute__((ext_vector_type(4))) float f32x4;
typedef __attribute__((ext_vector_type(8))) unsigned short ushort8v;
typedef __attribute__((ext_vector_type(4))) unsigned short ushort4v;
typedef _Float16 half8 __attribute__((ext_vector_type(8)));

__device__ __forceinline__ ushort f2bf(float f) {
    unsigned u = __float_as_uint(f);
    unsigned r = (u + 0x7fffu + ((u >> 16) & 1u)) >> 16;
    return (ushort)r;
}
__device__ __forceinline__ float bf2f(ushort h) {
    return __uint_as_float(((unsigned)h) << 16);
}
__device__ __forceinline__ ushort f2h(float f) {
    _Float16 h = (_Float16)f;
    return __builtin_bit_cast(ushort, h);
}
__device__ __forceinline__ float h2f(ushort u) {
    return (float)__builtin_bit_cast(_Float16, u);
}

// ---------------- phase 1: bin edges by dst>>9, coalesced line-exclusive flush ----

__global__ __launch_bounds__(256) void k_bin(const int* __restrict__ e0,
                                             const int* __restrict__ e1,
                                             const int* __restrict__ e2,
                                             int* __restrict__ g_cur,
                                             unsigned* __restrict__ g_bins) {
    const int br = blockIdx.x / P1B;
    const int cb = blockIdx.x % P1B;
    const int* ep = (br == 0 ? e0 : br == 1 ? e1 : e2);
    const int tid = threadIdx.x;
    const int e_base = cb * EPB;

    __shared__ int s_cnt[BINS];
    __shared__ int s_start[BINS];
    __shared__ int s_cur[BINS];
    __shared__ int s_gb[BINS];
    __shared__ unsigned s_stage[EPB];

    if (tid < BINS) s_cnt[tid] = 0;
    __syncthreads();

    int4 s4[4], d4[4];
    bool valid[4];
#pragma unroll
    for (int i = 0; i < 4; ++i) {
        int idx = e_base + i * 1024 + tid * 4;
        valid[i] = (idx < NE);  // idx%4==0, NE%4==0 -> full int4 valid
        if (valid[i]) {
            s4[i] = *(const int4*)&ep[idx];
            d4[i] = *(const int4*)&ep[NE + idx];
            atomicAdd(&s_cnt[d4[i].x >> 9], 1);
            atomicAdd(&s_cnt[d4[i].y >> 9], 1);
            atomicAdd(&s_cnt[d4[i].z >> 9], 1);
            atomicAdd(&s_cnt[d4[i].w >> 9], 1);
        }
    }
    __syncthreads();
    if (tid == 0) {
        int run = 0;
        for (int b = 0; b < BINS; ++b) {
            s_start[b] = run;
            run += s_cnt[b];
        }
    }
    __syncthreads();
    if (tid < BINS) {
        s_cur[tid] = s_start[tid];
        int c = s_cnt[tid];
        int pc = (c + 15) & ~15;  // 64B-aligned reservation
        s_gb[tid] = (c > 0) ? atomicAdd(&g_cur[br * BINS + tid], pc) : 0;
    }
    __syncthreads();

#pragma unroll
    for (int i = 0; i < 4; ++i) {
        if (valid[i]) {
            int ss[4] = {s4[i].x, s4[i].y, s4[i].z, s4[i].w};
            int dd[4] = {d4[i].x, d4[i].y, d4[i].z, d4[i].w};
#pragma unroll
            for (int q = 0; q < 4; ++q) {
                int bin = dd[q] >> 9;
                int pos = atomicAdd(&s_cur[bin], 1);
                s_stage[pos] = ((unsigned)(dd[q] & 511) << 16) | (unsigned)ss[q];
            }
        }
    }
    __syncthreads();

    for (int b = 0; b < BINS; ++b) {
        int c = s_cnt[b];
        if (c == 0) continue;
        int st = s_start[b];
        int gb = s_gb[b];
        int pc = (c + 15) & ~15;
        if (gb + pc > CAP) pc = (gb < CAP) ? (CAP - gb) : 0;  // overflow guard
        size_t obase = (size_t)(br * BINS + b) * CAP + gb;
        for (int j = tid; j < pc; j += 256)
            g_bins[obase + j] = (j < c) ? s_stage[st + j] : 0x80000000u;
    }
}

// ---------------- phase 2: per-bin CSR build with LDS atomics ----------------

__device__ __forceinline__ int wave_incl_scan(int v, int lane) {
#pragma unroll
    for (int d = 1; d < 64; d <<= 1) {
        int u = __shfl_up(v, d);
        if (lane >= d) v += u;
    }
    return v;
}

__global__ __launch_bounds__(256) void k_build(const unsigned* __restrict__ g_bins,
                                               const int* __restrict__ g_cur,
                                               ushort* __restrict__ g_csr,
                                               int* __restrict__ seg3,
                                               int* __restrict__ cnt3,
                                               float* __restrict__ dinv3) {
    const int bid = blockIdx.x;  // branch*BINS + bin
    const int br = bid / BINS;
    const int b2 = bid % BINS;
    const size_t base = (size_t)bid * CAP;
    const int node0 = b2 << 9;
    const int tid = threadIdx.x;

    __shared__ int s_cnt[512];
    __shared__ int s_off[512];
    __shared__ int s_wsum[4];

    s_cnt[tid] = 0;
    s_cnt[tid + 256] = 0;
    __syncthreads();

    const int total = min(g_cur[bid], CAP);
    for (int j = tid; j < total; j += 256) {
        unsigned p = g_bins[base + j];
        if (!(p & 0x80000000u)) atomicAdd(&s_cnt[(p >> 16) & 0x1FF], 1);
    }
    __syncthreads();

    // exclusive scan of 512 counts (pairs per thread + wave scan)
    const int lane = tid & 63, w = tid >> 6;
    int c0 = s_cnt[2 * tid], c1 = s_cnt[2 * tid + 1];
    int c2 = c0 + c1;
    int incl = wave_incl_scan(c2, lane);
    if (lane == 63) s_wsum[w] = incl;
    __syncthreads();
    int wpre = 0;
    for (int i = 0; i < w; ++i) wpre += s_wsum[i];
    int ex = wpre + incl - c2;
    s_off[2 * tid] = ex;
    s_off[2 * tid + 1] = ex + c0;

#pragma unroll
    for (int q = 0; q < 2; ++q) {
        int local = 2 * tid + q;
        int node = node0 + local;
        if (node < NN) {
            int g = br * NN + node;
            int c = (q == 0) ? c0 : c1;
            seg3[g] = (int)base + s_off[local];
            cnt3[g] = c;
            dinv3[g] = rsqrtf((float)(c + 1));
        }
    }
    __syncthreads();
    // cursors
    s_cnt[2 * tid] = s_off[2 * tid];
    s_cnt[2 * tid + 1] = s_off[2 * tid + 1];
    __syncthreads();

    for (int j = tid; j < total; j += 256) {
        unsigned p = g_bins[base + j];
        if (!(p & 0x80000000u)) {
            int loc = (p >> 16) & 0x1FF;
            int pos = atomicAdd(&s_cnt[loc], 1);
            g_csr[base + pos] = (ushort)(p & 0xFFFFu);
        }
    }
}

// ---------------- conversions ----------------

__global__ __launch_bounds__(256) void k_conv_x(const float* __restrict__ x,
                                                ushort* __restrict__ xp) {
    const int wid = threadIdx.x >> 6, lane = threadIdx.x & 63;
    const int row = blockIdx.x * 4 + wid;
    if (row >= NN) return;
    float4 v = *(const float4*)&x[(size_t)row * 256 + lane * 4];
    ushort4 hi, lo;
    hi.x = f2bf(v.x); lo.x = f2bf(v.x - bf2f(hi.x));
    hi.y = f2bf(v.y); lo.y = f2bf(v.y - bf2f(hi.y));
    hi.z = f2bf(v.z); lo.z = f2bf(v.z - bf2f(hi.z));
    hi.w = f2bf(v.w); lo.w = f2bf(v.w - bf2f(hi.w));
    *(ushort4*)&xp[(size_t)row * 512 + lane * 4] = hi;
    *(ushort4*)&xp[(size_t)row * 512 + 256 + lane * 4] = lo;
}

__global__ __launch_bounds__(256) void k_conv_w1(const float* __restrict__ w0,
                                                 const float* __restrict__ w1,
                                                 const float* __restrict__ w2,
                                                 ushort* __restrict__ BT1all) {
    int idx = blockIdx.x * 256 + threadIdx.x;  // 3 * 65536
    int b = idx >> 16, r = idx & 65535;
    int k = r >> 8, n = r & 255;
    const float* W = (b == 0 ? w0 : b == 1 ? w1 : w2);
    float w = W[r];
    ushort hi = f2bf(w);
    ushort lo = f2bf(w - bf2f(hi));
    ushort* row = BT1all + (size_t)b * 196608 + (size_t)n * 768;
    row[k] = hi;
    row[256 + k] = hi;
    row[512 + k] = lo;
}

__global__ __launch_bounds__(256) void k_conv_w2(const float* __restrict__ w0,
                                                 const float* __restrict__ w1,
                                                 const float* __restrict__ w2,
                                                 ushort* __restrict__ BT2all) {
    int idx = blockIdx.x * 256 + threadIdx.x;  // 3 * 32768
    int b = idx >> 15, r = idx & 32767;
    int k = r >> 7, n = r & 127;
    const float* W = (b == 0 ? w0 : b == 1 ? w1 : w2);
    BT2all[(size_t)b * 32768 + (size_t)n * 256 + k] = f2h(W[r]);
}

// ---------------- MFMA GEMM: 2-phase double-buffered pipeline ----------------
// C16[M x N] = (A @ BT^T) * dinv[row]; bf16x3 (KK>AK, hi-block reuse) or fp16.
// One __syncthreads per K-step: stage(t+1) issued BEFORE compute(t); the
// barrier's vmcnt(0) drain lands after MFMA has hidden the load latency.

template <int BM, int BN, int N, int KK, int AK, bool HALF>
__global__ __launch_bounds__((BM / 64) * (BN / 64) * 64) void k_gemm(
    const ushort* __restrict__ A, size_t aBatch,
    const ushort* __restrict__ BTall, int btBatch,
    const float* __restrict__ dinv3, ushort* __restrict__ Call, size_t cBatch) {
    constexpr int WGN = BN / 64, NW = (BM / 64) * WGN;
    constexpr int BK = 32;
    constexpr int MT = (NN + BM - 1) / BM, NT = N / BN, GB = MT * NT;
    constexpr int NSTEP = KK / BK;
    __shared__ ushort sA[2][BM * BK];
    __shared__ ushort sB[2][BN * BK];
    const int kb = blockIdx.x / GB;
    const int bid = blockIdx.x % GB;
    const ushort* Ab = A + (size_t)kb * aBatch;
    const ushort* BT = BTall + (size_t)kb * btBatch;
    const float* dinv = dinv3 + (size_t)kb * NN;
    ushort* C = Call + (size_t)kb * cBatch;
    const int t = threadIdx.x, lane = t & 63, wid = t >> 6;
    const int wm = (wid / WGN) * 64, wn = (wid % WGN) * 64;
    const int bm = (bid / NT) * BM;
    const int bn = (bid % NT) * BN;

    f32x4 zero = {0.f, 0.f, 0.f, 0.f};
    f32x4 acc[4][4];
#pragma unroll
    for (int m = 0; m < 4; ++m)
#pragma unroll
        for (int n = 0; n < 4; ++n) acc[m][n] = zero;

    constexpr int A_ISS = (BM * BK * 2) / (NW * 1024);
    constexpr int B_ISS = (BN * BK * 2) / (NW * 1024);

    auto stage = [&](int buf, int kt) {
        const int akt = (kt >= AK) ? kt - AK : kt;  // A hi-block reuse
#pragma unroll
        for (int i = 0; i < A_ISS; ++i) {
            int off = (wid + i * NW) << 10;
            int la = off + lane * 16;
            int row = la >> 6;
            int slot = (la >> 4) & 3;
            int scol = (slot ^ (row & 3)) << 4;
            int grow = bm + row;
            if (grow > NN - 1) grow = NN - 1;
            const char* ga = (const char*)Ab + (size_t)grow * (AK * 2) + akt * 2 + scol;
            __builtin_amdgcn_global_load_lds(
                (__attribute__((address_space(1))) const void*)ga,
                (__attribute__((address_space(3))) void*)((char*)sA[buf] + off), 16, 0, 0);
        }
#pragma unroll
        for (int i = 0; i < B_ISS; ++i) {
            int off = (wid + i * NW) << 10;
            int la = off + lane * 16;
            int row = la >> 6;
            int slot = (la >> 4) & 3;
            int scol = (slot ^ (row & 3)) << 4;
            const char* ga = (const char*)BT + (size_t)(bn + row) * (KK * 2) + kt * 2 + scol;
            __builtin_amdgcn_global_load_lds(
                (__attribute__((address_space(1))) const void*)ga,
                (__attribute__((address_space(3))) void*)((char*)sB[buf] + off), 16, 0, 0);
        }
    };

    stage(0, 0);
    __syncthreads();  // drain prologue loads

    int cur = 0;
    for (int ts = 0; ts < NSTEP; ++ts) {
        if (ts + 1 < NSTEP) stage(cur ^ 1, (ts + 1) * BK);  // overlap with MFMA

        const int s = lane >> 4;
        const int r0 = lane & 15;
        short8 af[4], bf[4];
#pragma unroll
        for (int m = 0; m < 4; ++m) {
            int row = wm + m * 16 + r0;
            af[m] = *(const short8*)((const char*)sA[cur] + row * 64 + ((s ^ (row & 3)) << 4));
        }
#pragma unroll
        for (int n = 0; n < 4; ++n) {
            int row = wn + n * 16 + r0;
            bf[n] = *(const short8*)((const char*)sB[cur] + row * 64 + ((s ^ (row & 3)) << 4));
        }
#pragma unroll
        for (int m = 0; m < 4; ++m)
#pragma unroll
            for (int n = 0; n < 4; ++n) {
                if constexpr (HALF)
                    acc[m][n] = __builtin_amdgcn_mfma_f32_16x16x32_f16(
                        __builtin_bit_cast(half8, af[m]), __builtin_bit_cast(half8, bf[n]),
                        acc[m][n], 0, 0, 0);
                else
                    acc[m][n] = __builtin_amdgcn_mfma_f32_16x16x32_bf16(af[m], bf[n],
                                                                        acc[m][n], 0, 0, 0);
            }
        __syncthreads();  // drains vmcnt(0): next tile staged & visible
        cur ^= 1;
    }

    const int cr0 = (lane >> 4) * 4;
    const int cc = lane & 15;
#pragma unroll
    for (int m = 0; m < 4; ++m) {
#pragma unroll
        for (int r = 0; r < 4; ++r) {
            int row = bm + wm + m * 16 + cr0 + r;
            if (row < NN) {
                float dv = dinv[row];
#pragma unroll
                for (int n = 0; n < 4; ++n)
                    C[(size_t)row * N + bn + wn + n * 16 + cc] = f2h(acc[m][n][r] * dv);
            }
        }
    }
}

// ---------------- layer-1 aggregation (batched over 3 branches) ----------------

__global__ __launch_bounds__(256) void k_agg1(const ushort* __restrict__ hs16all,
                                              const int* __restrict__ seg3,
                                              const int* __restrict__ cnt3,
                                              const ushort* __restrict__ g_csr,
                                              const float* __restrict__ dinv3,
                                              const float* __restrict__ b1a,
                                              const float* __restrict__ b1b,
                                              const float* __restrict__ b1c,
                                              ushort* __restrict__ h1all) {
    constexpr int WBn = (NN + 3) / 4;
    const int b = blockIdx.x / WBn;
    const int blk = blockIdx.x % WBn;
    const int wid = threadIdx.x >> 6;
    const int lane = threadIdx.x & 63;
    const int node = blk * 4 + wid;
    if (node >= NN) return;
    const int half = lane >> 5, l32 = lane & 31;
    const int g = b * NN + node;
    const ushort* hs = hs16all + (size_t)b * NN * 256;
    const ushort* csr = g_csr + seg3[g];
    const int len = cnt3[g] + 1;
    const size_t colb = (size_t)l32 * 8;

    float acc[8] = {0.f, 0.f, 0.f, 0.f, 0.f, 0.f, 0.f, 0.f};
    int i = half;
    for (; i + 6 < len; i += 8) {
        int s0 = (i == 0) ? node : (int)csr[i - 1];
        int s1 = (int)csr[i + 1];
        int s2 = (int)csr[i + 3];
        int s3 = (int)csr[i + 5];
        ushort8v v0 = *(const ushort8v*)&hs[(size_t)s0 * 256 + colb];
        ushort8v v1 = *(const ushort8v*)&hs[(size_t)s1 * 256 + colb];
        ushort8v v2 = *(const ushort8v*)&hs[(size_t)s2 * 256 + colb];
        ushort8v v3 = *(const ushort8v*)&hs[(size_t)s3 * 256 + colb];
#pragma unroll
        for (int j = 0; j < 8; ++j)
            acc[j] += (h2f(v0[j]) + h2f(v1[j])) + (h2f(v2[j]) + h2f(v3[j]));
    }
    for (; i < len; i += 2) {
        int s = (i == 0) ? node : (int)csr[i - 1];
        ushort8v v = *(const ushort8v*)&hs[(size_t)s * 256 + colb];
#pragma unroll
        for (int j = 0; j < 8; ++j) acc[j] += h2f(v[j]);
    }
#pragma unroll
    for (int j = 0; j < 8; ++j) acc[j] += __shfl_xor(acc[j], 32);

    if (half == 0) {
        const float* bias = (b == 0 ? b1a : b == 1 ? b1b : b1c);
        const float di = dinv3[g];
        ushort8v o;
#pragma unroll
        for (int j = 0; j < 8; ++j) {
            float r = fmaxf(di * acc[j] + bias[l32 * 8 + j], 0.f);
            o[j] = f2h(r);
        }
        *(ushort8v*)&h1all[((size_t)b * NN + node) * 256 + colb] = o;
    }
}

// ---------------- fused layer-2 aggregation (x3) + attention ----------------

__global__ __launch_bounds__(256) void k_final(const ushort* __restrict__ hs2all,
                                               const int* __restrict__ seg3,
                                               const int* __restrict__ cnt3,
                                               const ushort* __restrict__ g_csr,
                                               const float* __restrict__ dinv3,
                                               const float* __restrict__ b2a,
                                               const float* __restrict__ b2b,
                                               const float* __restrict__ b2c,
                                               const float* __restrict__ attn_w,
                                               const float* __restrict__ attn_b,
                                               float* __restrict__ out) {
    const int wid = threadIdx.x >> 6;
    const int lane = threadIdx.x & 63;
    const int node = blockIdx.x * 4 + wid;
    if (node >= NN) return;
    const int half = lane >> 5, l32 = lane & 31;
    const size_t colb = (size_t)l32 * 4;

    float f[3][4];
#pragma unroll
    for (int b = 0; b < 3; ++b) {
        const int g = b * NN + node;
        const ushort* hs = hs2all + (size_t)b * NN * 128;
        const ushort* csr = g_csr + seg3[g];
        const int len = cnt3[g] + 1;
        float acc[4] = {0.f, 0.f, 0.f, 0.f};
        int i = half;
        for (; i + 6 < len; i += 8) {
            int s0 = (i == 0) ? node : (int)csr[i - 1];
            int s1 = (int)csr[i + 1];
            int s2 = (int)csr[i + 3];
            int s3 = (int)csr[i + 5];
            ushort4v v0 = *(const ushort4v*)&hs[(size_t)s0 * 128 + colb];
            ushort4v v1 = *(const ushort4v*)&hs[(size_t)s1 * 128 + colb];
            ushort4v v2 = *(const ushort4v*)&hs[(size_t)s2 * 128 + colb];
            ushort4v v3 = *(const ushort4v*)&hs[(size_t)s3 * 128 + colb];
#pragma unroll
            for (int j = 0; j < 4; ++j)
                acc[j] += (h2f(v0[j]) + h2f(v1[j])) + (h2f(v2[j]) + h2f(v3[j]));
        }
        for (; i < len; i += 2) {
            int s = (i == 0) ? node : (int)csr[i - 1];
            ushort4v v = *(const ushort4v*)&hs[(size_t)s * 128 + colb];
#pragma unroll
            for (int j = 0; j < 4; ++j) acc[j] += h2f(v[j]);
        }
#pragma unroll
        for (int j = 0; j < 4; ++j) acc[j] += __shfl_xor(acc[j], 32);
        const float* bias = (b == 0 ? b2a : b == 1 ? b2b : b2c);
        const float di = dinv3[g];
#pragma unroll
        for (int j = 0; j < 4; ++j) f[b][j] = di * acc[j] + bias[l32 * 4 + j];
    }

    float4 w = *(const float4*)&attn_w[l32 * 4];
    float s0 = f[0][0] * w.x + f[0][1] * w.y + f[0][2] * w.z + f[0][3] * w.w;
    float s1 = f[1][0] * w.x + f[1][1] * w.y + f[1][2] * w.z + f[1][3] * w.w;
    float s2 = f[2][0] * w.x + f[2][1] * w.y + f[2][2] * w.z + f[2][3] * w.w;
#pragma unroll
    for (int m = 16; m >= 1; m >>= 1) {
        s0 += __shfl_xor(s0, m);
        s1 += __shfl_xor(s1, m);
        s2 += __shfl_xor(s2, m);
    }
    float bb = attn_b[0];
    s0 += bb; s1 += bb; s2 += bb;
    float mx = fmaxf(s0, fmaxf(s1, s2));
    float e0 = expf(s0 - mx), e1 = expf(s1 - mx), e2 = expf(s2 - mx);
    float inv = 1.f / (e0 + e1 + e2);
    e0 *= inv; e1 *= inv; e2 *= inv;

    if (half == 0) {
        float4 o;
        o.x = f[0][0] * e0 + f[1][0] * e1 + f[2][0] * e2;
        o.y = f[0][1] * e0 + f[1][1] * e1 + f[2][1] * e2;
        o.z = f[0][2] * e0 + f[1][2] * e1 + f[2][2] * e2;
        o.w = f[0][3] * e0 + f[1][3] * e1 + f[2][3] * e2;
        *(float4*)&out[(size_t)node * 128 + colb] = o;
    }
}

// ---------------- launch ----------------

extern "C" void kernel_launch(void* const* d_in, const int* in_sizes, int n_in,
                              void* d_out, int out_size, void* d_ws, size_t ws_size,
                              hipStream_t stream) {
    const float* x = (const float*)d_in[0];
    const int* e0 = (const int*)d_in[1];
    const int* e1 = (const int*)d_in[2];
    const int* e2 = (const int*)d_in[3];
    const float* attn_w = (const float*)d_in[16];
    const float* attn_b = (const float*)d_in[17];

    char* ws = (char*)d_ws;
    size_t off = 0;
    auto alloc = [&](size_t bytes) -> void* {
        void* p = ws + off;
        off += (bytes + 255) & ~(size_t)255;
        return p;
    };

    int* g_cur      = (int*)alloc(3 * BINS * 4);                 // zeroed
    int* seg3       = (int*)alloc((size_t)3 * NN * 4);
    int* cnt3       = (int*)alloc((size_t)3 * NN * 4);
    float* dinv3    = (float*)alloc((size_t)3 * NN * 4);
    ushort* g_csr   = (ushort*)alloc((size_t)3 * BINS * CAP * 2);  // 7.2 MB
    ushort* xp      = (ushort*)alloc((size_t)NN * 512 * 2);       // 51.2 MB
    ushort* hs2all  = xp;  // alias: xp dead after gemm1; hs2 (38.4 MB) fits
    ushort* hs16all = (ushort*)alloc((size_t)3 * NN * 256 * 2);   // 76.8 MB
    ushort* h1all   = (ushort*)alloc((size_t)3 * NN * 256 * 2);   // 76.8 MB
    unsigned* g_bins = (unsigned*)h1all;  // alias: g_bins dead before h1all written
    ushort* BT1all  = (ushort*)alloc((size_t)3 * 256 * 768 * 2);
    ushort* BT2all  = (ushort*)alloc((size_t)3 * 128 * 256 * 2);

    const int WB = (NN + 3) / 4;  // 12500

    hipMemsetAsync(g_cur, 0, 3 * BINS * 4, stream);
    k_conv_x<<<WB, 256, 0, stream>>>(x, xp);
    k_conv_w1<<<768, 256, 0, stream>>>((const float*)d_in[4], (const float*)d_in[8],
                                       (const float*)d_in[12], BT1all);
    k_conv_w2<<<384, 256, 0, stream>>>((const float*)d_in[6], (const float*)d_in[10],
                                       (const float*)d_in[14], BT2all);

    k_bin<<<3 * P1B, 256, 0, stream>>>(e0, e1, e2, g_cur, g_bins);
    k_build<<<3 * BINS, 256, 0, stream>>>(g_bins, g_cur, g_csr, seg3, cnt3, dinv3);

    // layer 1: hs = dinv*(x @ W1) bf16x3 -> fp16; BN=256 => each A-panel read once
    k_gemm<128, 256, 256, 768, 512, false><<<3 * 391, 512, 0, stream>>>(
        xp, 0, BT1all, 196608, dinv3, hs16all, (size_t)NN * 256);
    k_agg1<<<3 * WB, 256, 0, stream>>>(hs16all, seg3, cnt3, g_csr, dinv3,
                                       (const float*)d_in[5], (const float*)d_in[9],
                                       (const float*)d_in[13], h1all);

    // layer 2: hs2 = dinv*(h1 @ W2) fp16
    k_gemm<128, 128, 128, 256, 256, true><<<3 * 391, 256, 0, stream>>>(
        h1all, (size_t)NN * 256, BT2all, 32768, dinv3, hs2all, (size_t)NN * 128);

    // fused layer-2 aggregation + attention
    k_final<<<WB, 256, 0, stream>>>(hs2all, seg3, cnt3, g_csr, dinv3,
                                    (const float*)d_in[7], (const float*)d_in[11],
                                    (const float*)d_in[15], attn_w, attn_b,
                                    (float*)d_out);
}

// Round 9
// 475.609 us; speedup vs baseline: 1.1850x; 1.0160x over previous
//
#include <hip/hip_runtime.h>

#define NN 50000
#define NE 800000
#define BINS 98      // bins of 512 nodes per branch
#define CAP 12288    // per-bin capacity (u32 records / ushort csr entries)
#define EPB 4096     // edges per phase-1 block
#define P1B ((NE + EPB - 1) / EPB)  // 196 blocks per branch

typedef __attribute__((ext_vector_type(8))) short short8;
typedef __attribute__((ext_vector_type(4))) float f32x4;
typedef __attribute__((ext_vector_type(8))) unsigned short ushort8v;
typedef __attribute__((ext_vector_type(4))) unsigned short ushort4v;
typedef _Float16 half8 __attribute__((ext_vector_type(8)));

__device__ __forceinline__ ushort f2bf(float f) {
    unsigned u = __float_as_uint(f);
    unsigned r = (u + 0x7fffu + ((u >> 16) & 1u)) >> 16;
    return (ushort)r;
}
__device__ __forceinline__ float bf2f(ushort h) {
    return __uint_as_float(((unsigned)h) << 16);
}
__device__ __forceinline__ ushort f2h(float f) {
    _Float16 h = (_Float16)f;
    return __builtin_bit_cast(ushort, h);
}
__device__ __forceinline__ float h2f(ushort u) {
    return (float)__builtin_bit_cast(_Float16, u);
}

// ---------------- phase 1: bin edges by dst>>9, coalesced line-exclusive flush ----

__global__ __launch_bounds__(256) void k_bin(const int* __restrict__ e0,
                                             const int* __restrict__ e1,
                                             const int* __restrict__ e2,
                                             int* __restrict__ g_cur,
                                             unsigned* __restrict__ g_bins) {
    const int br = blockIdx.x / P1B;
    const int cb = blockIdx.x % P1B;
    const int* ep = (br == 0 ? e0 : br == 1 ? e1 : e2);
    const int tid = threadIdx.x;
    const int e_base = cb * EPB;

    __shared__ int s_cnt[BINS];
    __shared__ int s_start[BINS];
    __shared__ int s_cur[BINS];
    __shared__ int s_gb[BINS];
    __shared__ unsigned s_stage[EPB];

    if (tid < BINS) s_cnt[tid] = 0;
    __syncthreads();

    int4 s4[4], d4[4];
    bool valid[4];
#pragma unroll
    for (int i = 0; i < 4; ++i) {
        int idx = e_base + i * 1024 + tid * 4;
        valid[i] = (idx < NE);  // idx%4==0, NE%4==0 -> full int4 valid
        if (valid[i]) {
            s4[i] = *(const int4*)&ep[idx];
            d4[i] = *(const int4*)&ep[NE + idx];
            atomicAdd(&s_cnt[d4[i].x >> 9], 1);
            atomicAdd(&s_cnt[d4[i].y >> 9], 1);
            atomicAdd(&s_cnt[d4[i].z >> 9], 1);
            atomicAdd(&s_cnt[d4[i].w >> 9], 1);
        }
    }
    __syncthreads();
    if (tid == 0) {
        int run = 0;
        for (int b = 0; b < BINS; ++b) {
            s_start[b] = run;
            run += s_cnt[b];
        }
    }
    __syncthreads();
    if (tid < BINS) {
        s_cur[tid] = s_start[tid];
        int c = s_cnt[tid];
        int pc = (c + 15) & ~15;  // 64B-aligned reservation
        s_gb[tid] = (c > 0) ? atomicAdd(&g_cur[br * BINS + tid], pc) : 0;
    }
    __syncthreads();

#pragma unroll
    for (int i = 0; i < 4; ++i) {
        if (valid[i]) {
            int ss[4] = {s4[i].x, s4[i].y, s4[i].z, s4[i].w};
            int dd[4] = {d4[i].x, d4[i].y, d4[i].z, d4[i].w};
#pragma unroll
            for (int q = 0; q < 4; ++q) {
                int bin = dd[q] >> 9;
                int pos = atomicAdd(&s_cur[bin], 1);
                s_stage[pos] = ((unsigned)(dd[q] & 511) << 16) | (unsigned)ss[q];
            }
        }
    }
    __syncthreads();

    for (int b = 0; b < BINS; ++b) {
        int c = s_cnt[b];
        if (c == 0) continue;
        int st = s_start[b];
        int gb = s_gb[b];
        int pc = (c + 15) & ~15;
        if (gb + pc > CAP) pc = (gb < CAP) ? (CAP - gb) : 0;  // overflow guard
        size_t obase = (size_t)(br * BINS + b) * CAP + gb;
        for (int j = tid; j < pc; j += 256)
            g_bins[obase + j] = (j < c) ? s_stage[st + j] : 0x80000000u;
    }
}

// ---------------- phase 2: per-bin CSR build with LDS atomics ----------------

__device__ __forceinline__ int wave_incl_scan(int v, int lane) {
#pragma unroll
    for (int d = 1; d < 64; d <<= 1) {
        int u = __shfl_up(v, d);
        if (lane >= d) v += u;
    }
    return v;
}

__global__ __launch_bounds__(256) void k_build(const unsigned* __restrict__ g_bins,
                                               const int* __restrict__ g_cur,
                                               ushort* __restrict__ g_csr,
                                               int* __restrict__ seg3,
                                               int* __restrict__ cnt3,
                                               float* __restrict__ dinv3) {
    const int bid = blockIdx.x;  // branch*BINS + bin
    const int br = bid / BINS;
    const int b2 = bid % BINS;
    const size_t base = (size_t)bid * CAP;
    const int node0 = b2 << 9;
    const int tid = threadIdx.x;

    __shared__ int s_cnt[512];
    __shared__ int s_off[512];
    __shared__ int s_wsum[4];

    s_cnt[tid] = 0;
    s_cnt[tid + 256] = 0;
    __syncthreads();

    const int total = min(g_cur[bid], CAP);
    for (int j = tid; j < total; j += 256) {
        unsigned p = g_bins[base + j];
        if (!(p & 0x80000000u)) atomicAdd(&s_cnt[(p >> 16) & 0x1FF], 1);
    }
    __syncthreads();

    // exclusive scan of 512 counts (pairs per thread + wave scan)
    const int lane = tid & 63, w = tid >> 6;
    int c0 = s_cnt[2 * tid], c1 = s_cnt[2 * tid + 1];
    int c2 = c0 + c1;
    int incl = wave_incl_scan(c2, lane);
    if (lane == 63) s_wsum[w] = incl;
    __syncthreads();
    int wpre = 0;
    for (int i = 0; i < w; ++i) wpre += s_wsum[i];
    int ex = wpre + incl - c2;
    s_off[2 * tid] = ex;
    s_off[2 * tid + 1] = ex + c0;

#pragma unroll
    for (int q = 0; q < 2; ++q) {
        int local = 2 * tid + q;
        int node = node0 + local;
        if (node < NN) {
            int g = br * NN + node;
            int c = (q == 0) ? c0 : c1;
            seg3[g] = (int)base + s_off[local];
            cnt3[g] = c;
            dinv3[g] = rsqrtf((float)(c + 1));
        }
    }
    __syncthreads();
    // cursors
    s_cnt[2 * tid] = s_off[2 * tid];
    s_cnt[2 * tid + 1] = s_off[2 * tid + 1];
    __syncthreads();

    for (int j = tid; j < total; j += 256) {
        unsigned p = g_bins[base + j];
        if (!(p & 0x80000000u)) {
            int loc = (p >> 16) & 0x1FF;
            int pos = atomicAdd(&s_cnt[loc], 1);
            g_csr[base + pos] = (ushort)(p & 0xFFFFu);
        }
    }
}

// ---------------- conversions ----------------

__global__ __launch_bounds__(256) void k_conv_x(const float* __restrict__ x,
                                                ushort* __restrict__ xp) {
    const int wid = threadIdx.x >> 6, lane = threadIdx.x & 63;
    const int row = blockIdx.x * 4 + wid;
    if (row >= NN) return;
    float4 v = *(const float4*)&x[(size_t)row * 256 + lane * 4];
    ushort4 hi, lo;
    hi.x = f2bf(v.x); lo.x = f2bf(v.x - bf2f(hi.x));
    hi.y = f2bf(v.y); lo.y = f2bf(v.y - bf2f(hi.y));
    hi.z = f2bf(v.z); lo.z = f2bf(v.z - bf2f(hi.z));
    hi.w = f2bf(v.w); lo.w = f2bf(v.w - bf2f(hi.w));
    *(ushort4*)&xp[(size_t)row * 512 + lane * 4] = hi;
    *(ushort4*)&xp[(size_t)row * 512 + 256 + lane * 4] = lo;
}

__global__ __launch_bounds__(256) void k_conv_w1(const float* __restrict__ w0,
                                                 const float* __restrict__ w1,
                                                 const float* __restrict__ w2,
                                                 ushort* __restrict__ BT1all) {
    int idx = blockIdx.x * 256 + threadIdx.x;  // 3 * 65536
    int b = idx >> 16, r = idx & 65535;
    int k = r >> 8, n = r & 255;
    const float* W = (b == 0 ? w0 : b == 1 ? w1 : w2);
    float w = W[r];
    ushort hi = f2bf(w);
    ushort lo = f2bf(w - bf2f(hi));
    ushort* row = BT1all + (size_t)b * 196608 + (size_t)n * 768;
    row[k] = hi;
    row[256 + k] = hi;
    row[512 + k] = lo;
}

__global__ __launch_bounds__(256) void k_conv_w2(const float* __restrict__ w0,
                                                 const float* __restrict__ w1,
                                                 const float* __restrict__ w2,
                                                 ushort* __restrict__ BT2all) {
    int idx = blockIdx.x * 256 + threadIdx.x;  // 3 * 32768
    int b = idx >> 15, r = idx & 32767;
    int k = r >> 7, n = r & 127;
    const float* W = (b == 0 ? w0 : b == 1 ? w1 : w2);
    BT2all[(size_t)b * 32768 + (size_t)n * 256 + k] = f2h(W[r]);
}

// ---------------- MFMA GEMM: 2-phase double-buffered pipeline ----------------
// XSWZ: same M-tile's 3 branch-blocks land on the SAME XCD (blockIdx%8) and run
// back-to-back there -> shared A panel (xp) fetched ~once instead of 3x.

template <int BM, int BN, int N, int KK, int AK, bool HALF, bool XSWZ>
__global__ __launch_bounds__((BM / 64) * (BN / 64) * 64) void k_gemm(
    const ushort* __restrict__ A, size_t aBatch,
    const ushort* __restrict__ BTall, int btBatch,
    const float* __restrict__ dinv3, ushort* __restrict__ Call, size_t cBatch) {
    constexpr int WGN = BN / 64, NW = (BM / 64) * WGN;
    constexpr int BK = 32;
    constexpr int MT = (NN + BM - 1) / BM, NT = N / BN, GB = MT * NT;
    constexpr int NSTEP = KK / BK;
    __shared__ ushort sA[2][BM * BK];
    __shared__ ushort sB[2][BN * BK];
    int kb, bid;
    if constexpr (XSWZ) {
        int q = blockIdx.x >> 3, r = blockIdx.x & 7;
        bid = (q / 3) * 8 + r;   // M-tile
        kb = q % 3;              // branch
        if (bid >= GB) return;
    } else {
        kb = blockIdx.x / GB;
        bid = blockIdx.x % GB;
    }
    const ushort* Ab = A + (size_t)kb * aBatch;
    const ushort* BT = BTall + (size_t)kb * btBatch;
    const float* dinv = dinv3 + (size_t)kb * NN;
    ushort* C = Call + (size_t)kb * cBatch;
    const int t = threadIdx.x, lane = t & 63, wid = t >> 6;
    const int wm = (wid / WGN) * 64, wn = (wid % WGN) * 64;
    const int bm = (bid / NT) * BM;
    const int bn = (bid % NT) * BN;

    f32x4 zero = {0.f, 0.f, 0.f, 0.f};
    f32x4 acc[4][4];
#pragma unroll
    for (int m = 0; m < 4; ++m)
#pragma unroll
        for (int n = 0; n < 4; ++n) acc[m][n] = zero;

    constexpr int A_ISS = (BM * BK * 2) / (NW * 1024);
    constexpr int B_ISS = (BN * BK * 2) / (NW * 1024);

    auto stage = [&](int buf, int kt) {
        const int akt = (kt >= AK) ? kt - AK : kt;  // A hi-block reuse
#pragma unroll
        for (int i = 0; i < A_ISS; ++i) {
            int off = (wid + i * NW) << 10;
            int la = off + lane * 16;
            int row = la >> 6;
            int slot = (la >> 4) & 3;
            int scol = (slot ^ (row & 3)) << 4;
            int grow = bm + row;
            if (grow > NN - 1) grow = NN - 1;
            const char* ga = (const char*)Ab + (size_t)grow * (AK * 2) + akt * 2 + scol;
            __builtin_amdgcn_global_load_lds(
                (__attribute__((address_space(1))) const void*)ga,
                (__attribute__((address_space(3))) void*)((char*)sA[buf] + off), 16, 0, 0);
        }
#pragma unroll
        for (int i = 0; i < B_ISS; ++i) {
            int off = (wid + i * NW) << 10;
            int la = off + lane * 16;
            int row = la >> 6;
            int slot = (la >> 4) & 3;
            int scol = (slot ^ (row & 3)) << 4;
            const char* ga = (const char*)BT + (size_t)(bn + row) * (KK * 2) + kt * 2 + scol;
            __builtin_amdgcn_global_load_lds(
                (__attribute__((address_space(1))) const void*)ga,
                (__attribute__((address_space(3))) void*)((char*)sB[buf] + off), 16, 0, 0);
        }
    };

    stage(0, 0);
    __syncthreads();  // drain prologue loads

    int cur = 0;
    for (int ts = 0; ts < NSTEP; ++ts) {
        if (ts + 1 < NSTEP) stage(cur ^ 1, (ts + 1) * BK);  // overlap with MFMA

        const int s = lane >> 4;
        const int r0 = lane & 15;
        short8 af[4], bf[4];
#pragma unroll
        for (int m = 0; m < 4; ++m) {
            int row = wm + m * 16 + r0;
            af[m] = *(const short8*)((const char*)sA[cur] + row * 64 + ((s ^ (row & 3)) << 4));
        }
#pragma unroll
        for (int n = 0; n < 4; ++n) {
            int row = wn + n * 16 + r0;
            bf[n] = *(const short8*)((const char*)sB[cur] + row * 64 + ((s ^ (row & 3)) << 4));
        }
#pragma unroll
        for (int m = 0; m < 4; ++m)
#pragma unroll
            for (int n = 0; n < 4; ++n) {
                if constexpr (HALF)
                    acc[m][n] = __builtin_amdgcn_mfma_f32_16x16x32_f16(
                        __builtin_bit_cast(half8, af[m]), __builtin_bit_cast(half8, bf[n]),
                        acc[m][n], 0, 0, 0);
                else
                    acc[m][n] = __builtin_amdgcn_mfma_f32_16x16x32_bf16(af[m], bf[n],
                                                                        acc[m][n], 0, 0, 0);
            }
        __syncthreads();  // drains vmcnt(0): next tile staged & visible
        cur ^= 1;
    }

    const int cr0 = (lane >> 4) * 4;
    const int cc = lane & 15;
#pragma unroll
    for (int m = 0; m < 4; ++m) {
#pragma unroll
        for (int r = 0; r < 4; ++r) {
            int row = bm + wm + m * 16 + cr0 + r;
            if (row < NN) {
                float dv = dinv[row];
#pragma unroll
                for (int n = 0; n < 4; ++n)
                    C[(size_t)row * N + bn + wn + n * 16 + cc] = f2h(acc[m][n][r] * dv);
            }
        }
    }
}

// ---------------- layer-1 aggregation: XCD-affine (branch,node) partition ----
// blockIdx%8 ~ XCD (round-robin dispatch). Each XCD gets a contiguous slice of
// the 37500 (branch,node-block) units -> touches at most 2 branches' hs16
// instead of 3 -> cross-XCD fetch duplication 24 -> 10 touches.

#define UTOT (3 * 12500)

__global__ __launch_bounds__(256) void k_agg1(const ushort* __restrict__ hs16all,
                                              const int* __restrict__ seg3,
                                              const int* __restrict__ cnt3,
                                              const ushort* __restrict__ g_csr,
                                              const float* __restrict__ dinv3,
                                              const float* __restrict__ b1a,
                                              const float* __restrict__ b1b,
                                              const float* __restrict__ b1c,
                                              ushort* __restrict__ h1all) {
    const int x = blockIdx.x & 7, j = blockIdx.x >> 3;
    const int start = (x * UTOT) >> 3;
    const int end = ((x + 1) * UTOT) >> 3;
    const int u = start + j;
    if (u >= end) return;
    const int b = u / 12500;
    const int blk = u % 12500;

    const int wid = threadIdx.x >> 6;
    const int lane = threadIdx.x & 63;
    const int node = blk * 4 + wid;
    if (node >= NN) return;
    const int half = lane >> 5, l32 = lane & 31;
    const int g = b * NN + node;
    const ushort* hs = hs16all + (size_t)b * NN * 256;
    const ushort* csr = g_csr + seg3[g];
    const int len = cnt3[g] + 1;
    const size_t colb = (size_t)l32 * 8;

    float acc[8] = {0.f, 0.f, 0.f, 0.f, 0.f, 0.f, 0.f, 0.f};
    int i = half;
    for (; i + 6 < len; i += 8) {
        int s0 = (i == 0) ? node : (int)csr[i - 1];
        int s1 = (int)csr[i + 1];
        int s2 = (int)csr[i + 3];
        int s3 = (int)csr[i + 5];
        ushort8v v0 = *(const ushort8v*)&hs[(size_t)s0 * 256 + colb];
        ushort8v v1 = *(const ushort8v*)&hs[(size_t)s1 * 256 + colb];
        ushort8v v2 = *(const ushort8v*)&hs[(size_t)s2 * 256 + colb];
        ushort8v v3 = *(const ushort8v*)&hs[(size_t)s3 * 256 + colb];
#pragma unroll
        for (int jq = 0; jq < 8; ++jq)
            acc[jq] += (h2f(v0[jq]) + h2f(v1[jq])) + (h2f(v2[jq]) + h2f(v3[jq]));
    }
    for (; i < len; i += 2) {
        int s = (i == 0) ? node : (int)csr[i - 1];
        ushort8v v = *(const ushort8v*)&hs[(size_t)s * 256 + colb];
#pragma unroll
        for (int jq = 0; jq < 8; ++jq) acc[jq] += h2f(v[jq]);
    }
#pragma unroll
    for (int jq = 0; jq < 8; ++jq) acc[jq] += __shfl_xor(acc[jq], 32);

    if (half == 0) {
        const float* bias = (b == 0 ? b1a : b == 1 ? b1b : b1c);
        const float di = dinv3[g];
        ushort8v o;
#pragma unroll
        for (int jq = 0; jq < 8; ++jq) {
            float r = fmaxf(di * acc[jq] + bias[l32 * 8 + jq], 0.f);
            o[jq] = f2h(r);
        }
        *(ushort8v*)&h1all[((size_t)b * NN + node) * 256 + colb] = o;
    }
}

// ---------------- fused layer-2 aggregation (x3) + attention ----------------

__global__ __launch_bounds__(256) void k_final(const ushort* __restrict__ hs2all,
                                               const int* __restrict__ seg3,
                                               const int* __restrict__ cnt3,
                                               const ushort* __restrict__ g_csr,
                                               const float* __restrict__ dinv3,
                                               const float* __restrict__ b2a,
                                               const float* __restrict__ b2b,
                                               const float* __restrict__ b2c,
                                               const float* __restrict__ attn_w,
                                               const float* __restrict__ attn_b,
                                               float* __restrict__ out) {
    const int wid = threadIdx.x >> 6;
    const int lane = threadIdx.x & 63;
    const int node = blockIdx.x * 4 + wid;
    if (node >= NN) return;
    const int half = lane >> 5, l32 = lane & 31;
    const size_t colb = (size_t)l32 * 4;

    float f[3][4];
#pragma unroll
    for (int b = 0; b < 3; ++b) {
        const int g = b * NN + node;
        const ushort* hs = hs2all + (size_t)b * NN * 128;
        const ushort* csr = g_csr + seg3[g];
        const int len = cnt3[g] + 1;
        float acc[4] = {0.f, 0.f, 0.f, 0.f};
        int i = half;
        for (; i + 6 < len; i += 8) {
            int s0 = (i == 0) ? node : (int)csr[i - 1];
            int s1 = (int)csr[i + 1];
            int s2 = (int)csr[i + 3];
            int s3 = (int)csr[i + 5];
            ushort4v v0 = *(const ushort4v*)&hs[(size_t)s0 * 128 + colb];
            ushort4v v1 = *(const ushort4v*)&hs[(size_t)s1 * 128 + colb];
            ushort4v v2 = *(const ushort4v*)&hs[(size_t)s2 * 128 + colb];
            ushort4v v3 = *(const ushort4v*)&hs[(size_t)s3 * 128 + colb];
#pragma unroll
            for (int j = 0; j < 4; ++j)
                acc[j] += (h2f(v0[j]) + h2f(v1[j])) + (h2f(v2[j]) + h2f(v3[j]));
        }
        for (; i < len; i += 2) {
            int s = (i == 0) ? node : (int)csr[i - 1];
            ushort4v v = *(const ushort4v*)&hs[(size_t)s * 128 + colb];
#pragma unroll
            for (int j = 0; j < 4; ++j) acc[j] += h2f(v[j]);
        }
#pragma unroll
        for (int j = 0; j < 4; ++j) acc[j] += __shfl_xor(acc[j], 32);
        const float* bias = (b == 0 ? b2a : b == 1 ? b2b : b2c);
        const float di = dinv3[g];
#pragma unroll
        for (int j = 0; j < 4; ++j) f[b][j] = di * acc[j] + bias[l32 * 4 + j];
    }

    float4 w = *(const float4*)&attn_w[l32 * 4];
    float s0 = f[0][0] * w.x + f[0][1] * w.y + f[0][2] * w.z + f[0][3] * w.w;
    float s1 = f[1][0] * w.x + f[1][1] * w.y + f[1][2] * w.z + f[1][3] * w.w;
    float s2 = f[2][0] * w.x + f[2][1] * w.y + f[2][2] * w.z + f[2][3] * w.w;
#pragma unroll
    for (int m = 16; m >= 1; m >>= 1) {
        s0 += __shfl_xor(s0, m);
        s1 += __shfl_xor(s1, m);
        s2 += __shfl_xor(s2, m);
    }
    float bb = attn_b[0];
    s0 += bb; s1 += bb; s2 += bb;
    float mx = fmaxf(s0, fmaxf(s1, s2));
    float e0 = expf(s0 - mx), e1 = expf(s1 - mx), e2 = expf(s2 - mx);
    float inv = 1.f / (e0 + e1 + e2);
    e0 *= inv; e1 *= inv; e2 *= inv;

    if (half == 0) {
        float4 o;
        o.x = f[0][0] * e0 + f[1][0] * e1 + f[2][0] * e2;
        o.y = f[0][1] * e0 + f[1][1] * e1 + f[2][1] * e2;
        o.z = f[0][2] * e0 + f[1][2] * e1 + f[2][2] * e2;
        o.w = f[0][3] * e0 + f[1][3] * e1 + f[2][3] * e2;
        *(float4*)&out[(size_t)node * 128 + colb] = o;
    }
}

// ---------------- launch ----------------

extern "C" void kernel_launch(void* const* d_in, const int* in_sizes, int n_in,
                              void* d_out, int out_size, void* d_ws, size_t ws_size,
                              hipStream_t stream) {
    const float* x = (const float*)d_in[0];
    const int* e0 = (const int*)d_in[1];
    const int* e1 = (const int*)d_in[2];
    const int* e2 = (const int*)d_in[3];
    const float* attn_w = (const float*)d_in[16];
    const float* attn_b = (const float*)d_in[17];

    char* ws = (char*)d_ws;
    size_t off = 0;
    auto alloc = [&](size_t bytes) -> void* {
        void* p = ws + off;
        off += (bytes + 255) & ~(size_t)255;
        return p;
    };

    int* g_cur      = (int*)alloc(3 * BINS * 4);                 // zeroed
    int* seg3       = (int*)alloc((size_t)3 * NN * 4);
    int* cnt3       = (int*)alloc((size_t)3 * NN * 4);
    float* dinv3    = (float*)alloc((size_t)3 * NN * 4);
    ushort* g_csr   = (ushort*)alloc((size_t)3 * BINS * CAP * 2);  // 7.2 MB
    ushort* xp      = (ushort*)alloc((size_t)NN * 512 * 2);       // 51.2 MB
    ushort* hs2all  = xp;  // alias: xp dead after gemm1; hs2 (38.4 MB) fits
    ushort* hs16all = (ushort*)alloc((size_t)3 * NN * 256 * 2);   // 76.8 MB
    ushort* h1all   = (ushort*)alloc((size_t)3 * NN * 256 * 2);   // 76.8 MB
    unsigned* g_bins = (unsigned*)h1all;  // alias: g_bins dead before h1all written
    ushort* BT1all  = (ushort*)alloc((size_t)3 * 256 * 768 * 2);
    ushort* BT2all  = (ushort*)alloc((size_t)3 * 128 * 256 * 2);

    const int WB = (NN + 3) / 4;  // 12500

    hipMemsetAsync(g_cur, 0, 3 * BINS * 4, stream);
    k_conv_x<<<WB, 256, 0, stream>>>(x, xp);
    k_conv_w1<<<768, 256, 0, stream>>>((const float*)d_in[4], (const float*)d_in[8],
                                       (const float*)d_in[12], BT1all);
    k_conv_w2<<<384, 256, 0, stream>>>((const float*)d_in[6], (const float*)d_in[10],
                                       (const float*)d_in[14], BT2all);

    k_bin<<<3 * P1B, 256, 0, stream>>>(e0, e1, e2, g_cur, g_bins);
    k_build<<<3 * BINS, 256, 0, stream>>>(g_bins, g_cur, g_csr, seg3, cnt3, dinv3);

    // layer 1: hs = dinv*(x @ W1) bf16x3 -> fp16; XCD-swizzled (shared A panels)
    k_gemm<128, 256, 256, 768, 512, false, true><<<1176, 512, 0, stream>>>(
        xp, 0, BT1all, 196608, dinv3, hs16all, (size_t)NN * 256);
    // XCD-affine partitioned aggregation: grid = 8 * ceil(37500/8)
    k_agg1<<<8 * ((UTOT + 7) / 8), 256, 0, stream>>>(
        hs16all, seg3, cnt3, g_csr, dinv3,
        (const float*)d_in[5], (const float*)d_in[9], (const float*)d_in[13], h1all);

    // layer 2: hs2 = dinv*(h1 @ W2) fp16 (A branch-specific, no swizzle)
    k_gemm<128, 128, 128, 256, 256, true, false><<<3 * 391, 256, 0, stream>>>(
        h1all, (size_t)NN * 256, BT2all, 32768, dinv3, hs2all, (size_t)NN * 128);

    // fused layer-2 aggregation + attention
    k_final<<<WB, 256, 0, stream>>>(hs2all, seg3, cnt3, g_csr, dinv3,
                                    (const float*)d_in[7], (const float*)d_in[11],
                                    (const float*)d_in[15], attn_w, attn_b,
                                    (float*)d_out);
}